// Round 9
// baseline (189.116 us; speedup 1.0000x reference)
//
#include <hip/hip_runtime.h>
#include <hip/hip_bf16.h>

#define JTOT  16384
#define BATCH 32
#define DD    32
#define AE    16
#define HH    128
#define EHD   256
#define LATD  32
#define JT    16      // j per block
#define NBLK  1024    // k_rows blocks
#define EPSV  1e-5f

// workspace layout (floats):
//   acc2[32][1024] pooled replicas, cnt2[32][32] counts  (zeroed)
//   AF: prepacked bf16 W2^T fragments, [8 (s,dt)][64 lane] x uint4
//   EP: per-lane epilogue params (64 lanes x 24 floats)
//   MW: mean(w0), mean(w0^2)
#define WS_ACC   0
#define WS_CNT   32768
#define WS_ZEND  33792   // floats to zero
#define WS_AF    33792   // 2048 floats (dword-punned)
#define WS_EP    35840   // 1536 floats
#define WS_MW    37376   // 2 floats

typedef __attribute__((ext_vector_type(8))) short short8;
typedef __attribute__((ext_vector_type(4))) float f32x4;
typedef __attribute__((ext_vector_type(2))) float v2f;

static __device__ __forceinline__ v2f mk2(float a, float b) {
    v2f r; r.x = a; r.y = b; return r;
}
static __device__ __forceinline__ v2f FMA2(v2f a, v2f b, v2f c) {
#if __has_builtin(__builtin_elementwise_fma)
    return __builtin_elementwise_fma(a, b, c);
#else
    v2f r; r.x = fmaf(a.x, b.x, c.x); r.y = fmaf(a.y, b.y, c.y); return r;
#endif
}
static __device__ __forceinline__ v2f MAX2(v2f a, v2f b) {
#if __has_builtin(__builtin_elementwise_max)
    return __builtin_elementwise_max(a, b);
#else
    v2f r; r.x = fmaxf(a.x, b.x); r.y = fmaxf(a.y, b.y); return r;
#endif
}

// LDS float offsets (k_rows)
#define OFF_BASE 0      // 16*132 = 2112
#define OFF_XS   2112   // 32*17  = 544
#define OFF_MS   2656   // 32*17  = 544
#define OFF_W0   3200   // 128
#define OFF_G1   3328   // 128
#define OFF_B1   3456   // 128
#define OFF_S0   3584   // 16
#define OFF_S1   3600   // 16
#define OFF_C1   3616   // 16
#define OFF_AF   4224   // 2048 dwords: Af fragments, [8][64] uint4
#define LDS_FLOATS 6272 // pool reduce reuses smem[0..4223]: 4 slots * 1056

__device__ __forceinline__ unsigned pk2(float lo, float hi) {
    float2 f; f.x = lo; f.y = hi;
    __hip_bfloat162 h = __float22bfloat162_rn(f);
    unsigned u; __builtin_memcpy(&u, &h, 4);
    return u;
}

// normalized-relu'd h1 for 2 consecutive k, packed to 2xbf16
__device__ __forceinline__ unsigned pke(v2f b, v2f w, v2f g, v2f Bl,
                                        float x, float rs, float cc) {
    v2f u = FMA2(mk2(x, x), w, b);            // h1 = base + x*w0
    v2f t = FMA2(u, mk2(rs, rs), mk2(cc, cc));
    v2f h = FMA2(t, g, Bl);
    h = MAX2(h, mk2(0.f, 0.f));
    return pk2(h.x, h.y);
}

// ---------------------------------------------------------------------------
// Kernel 0: blocks 0..32 zero the accumulator region (poisoned 0xAA each
// call). Block 33 precomputes block-invariant k_rows data: bf16 W2^T
// fragments ([8][64] uint4 so k_rows can LDS-stage them), epilogue params,
// w0 moments.
// ---------------------------------------------------------------------------
__global__ __launch_bounds__(256) void k_zero(
    float* __restrict__ ws, const float* __restrict__ hW1,
    const float* __restrict__ hW2, const float* __restrict__ hb2,
    const float* __restrict__ hg2, const float* __restrict__ hB2)
{
    if (blockIdx.x < 33) {
        int i = (blockIdx.x * 256 + threadIdx.x) * 4;
        *(float4*)(ws + i) = (float4){0.f, 0.f, 0.f, 0.f};
        return;
    }
    const int tid = threadIdx.x;
    if (tid >= 64) return;
    const int lane = tid, n = lane & 15, q = lane >> 4;

    // AF: A[m=d (dt*16+n)][k=32s+8q+i], packed pairs along k.
    // Layout [ (s*2+dt) ][ lane ] x uint4 -> k_rows lane reads stride-16B.
    uint4* afp = (uint4*)(ws + WS_AF);
    #pragma unroll
    for (int s = 0; s < 4; ++s)
        #pragma unroll
        for (int dt = 0; dt < 2; ++dt) {
            union { unsigned u[4]; uint4 q4; } t;
            #pragma unroll
            for (int p2 = 0; p2 < 4; ++p2) {
                int k0 = 32 * s + 8 * q + 2 * p2;
                t.u[p2] = pk2(hW2[(k0    ) * DD + dt * 16 + n],
                              hW2[(k0 + 1) * DD + dt * 16 + n]);
            }
            afp[(s * 2 + dt) * 64 + lane] = t.q4;
        }

    // EP: d = dt*16 + 4q + r
    float* epp = ws + WS_EP + lane * 24;
    #pragma unroll
    for (int dt = 0; dt < 2; ++dt)
        #pragma unroll
        for (int r = 0; r < 4; ++r) {
            int d = dt * 16 + 4 * q + r;
            epp[dt * 4 + r]      = hb2[d];
            epp[8 + dt * 4 + r]  = hg2[d];
            epp[16 + dt * 4 + r] = hB2[d];
        }

    // MW: mean(w0), mean(w0^2)
    {
        float a = hW1[lane], b = hW1[64 + lane];
        float s = a + b, qq = fmaf(a, a, b * b);
        #pragma unroll
        for (int m = 1; m < 64; m <<= 1) { s += __shfl_xor(s, m); qq += __shfl_xor(qq, m); }
        if (lane == 0) { ws[WS_MW] = s * (1.f / HH); ws[WS_MW + 1] = qq * (1.f / HH); }
    }
}

// ---------------------------------------------------------------------------
// Kernel 1: 1024 blocks x 256 threads, 16 j each. Transposed MFMA:
// A = W2^T (d x K, bf16, staged ws->LDS, shared by all 4 waves), B =
// normalized h1^T (K x b), C = d x b.
// Register budget (gfx950 unified VGPR+AGPR): keeping Af in regs cost 32
// arch VGPRs -> ~192 total -> 2 waves/EU (Occupancy 18%, measured R8).
// Af->LDS + __launch_bounds__(256,3) targets ~160 total -> 3 waves/EU.
// (256,4) caused spills -> 300 MB scratch traffic (measured R4).
// Tail: atomicAdd pooled tile into acc2[blk&31] (32-way replicated).
// ---------------------------------------------------------------------------
__global__ __launch_bounds__(256, 3) void k_rows(
    const float* __restrict__ x, const int* __restrict__ mask,
    const int* __restrict__ aidx, const float* __restrict__ F,
    const float* __restrict__ AeE, const float* __restrict__ hW1,
    const float* __restrict__ hb1, const float* __restrict__ hg1,
    const float* __restrict__ hB1, float* __restrict__ ws)
{
    __shared__ float smem[LDS_FLOATS];
    const int tid = threadIdx.x;
    const int j0  = blockIdx.x * JT;

    float* BASEp = smem + OFF_BASE;   // [16 j][132]
    float* XSp   = smem + OFF_XS;     // [32 b][17]
    float* MSp   = smem + OFF_MS;     // [32 b][17]
    float* W0p   = smem + OFF_W0;
    float* G1p   = smem + OFF_G1;
    float* B1p   = smem + OFF_B1;
    float* S0p   = smem + OFF_S0;
    float* S1p   = smem + OFF_S1;
    float* C1p   = smem + OFF_C1;
    const uint4* AFl = (const uint4*)(smem + OFF_AF);

    const int lane = tid & 63;
    const int n = lane & 15, q = lane >> 4;
    const int wslot = tid >> 6;

    // ---- stage Af fragments ws -> LDS (512 uint4, coalesced)
    {
        const uint4* afg = (const uint4*)(ws + WS_AF);
        uint4* afl = (uint4*)(smem + OFF_AF);
        #pragma unroll
        for (int o = tid; o < 512; o += 256) afl[o] = afg[o];
    }
    // ---- per-lane epilogue params (coalesced vector loads from ws)
    float hb2v[8], g2v[8], B2v[8];
    {
        const float4* ep4 = (const float4*)(ws + WS_EP + lane * 24);
        float4 a0 = ep4[0], a1 = ep4[1], a2 = ep4[2], a3 = ep4[3], a4 = ep4[4], a5 = ep4[5];
        hb2v[0]=a0.x; hb2v[1]=a0.y; hb2v[2]=a0.z; hb2v[3]=a0.w;
        hb2v[4]=a1.x; hb2v[5]=a1.y; hb2v[6]=a1.z; hb2v[7]=a1.w;
        g2v[0]=a2.x;  g2v[1]=a2.y;  g2v[2]=a2.z;  g2v[3]=a2.w;
        g2v[4]=a3.x;  g2v[5]=a3.y;  g2v[6]=a3.z;  g2v[7]=a3.w;
        B2v[0]=a4.x;  B2v[1]=a4.y;  B2v[2]=a4.z;  B2v[3]=a4.w;
        B2v[4]=a5.x;  B2v[5]=a5.y;  B2v[6]=a5.z;  B2v[7]=a5.w;
    }
    const float mw0v = ws[WS_MW], sw0v = ws[WS_MW + 1];

    // ---- stage x, mask, LN1 params
    for (int o = tid; o < 512; o += 256) {
        int b = o >> 4, jj = o & 15;
        XSp[b * 17 + jj] = x[b * JTOT + j0 + jj];
        MSp[b * 17 + jj] = (float)mask[b * JTOT + j0 + jj];
    }
    if (tid < HH) { W0p[tid] = hW1[tid]; G1p[tid] = hg1[tid]; B1p[tid] = hB1[tid]; }

    // ---- base[j][k] (b-independent part of layer 1), packed fp32 over j-pairs
    {
        const int kk = tid & 127;
        const int jh = tid >> 7;           // 0..1
        float w[48];
        #pragma unroll
        for (int i = 0; i < 48; ++i) w[i] = hW1[(1 + i) * HH + kk];
        const float hb1v = hb1[kk];
        #pragma unroll
        for (int pr = 0; pr < 4; ++pr) {
            const int jja = 4 * pr + jh, jjb = jja + 2;
            const float4* Fa = (const float4*)(F + (j0 + jja) * DD);
            const float4* Fb = (const float4*)(F + (j0 + jjb) * DD);
            const float4* Aa = (const float4*)(AeE + aidx[j0 + jja] * AE);
            const float4* Ab = (const float4*)(AeE + aidx[j0 + jjb] * AE);
            v2f acc = mk2(hb1v, hb1v);
            #pragma unroll
            for (int i4 = 0; i4 < 8; ++i4) {
                float4 fa = Fa[i4], fb = Fb[i4];
                acc = FMA2(mk2(fa.x, fb.x), mk2(w[i4*4+0], w[i4*4+0]), acc);
                acc = FMA2(mk2(fa.y, fb.y), mk2(w[i4*4+1], w[i4*4+1]), acc);
                acc = FMA2(mk2(fa.z, fb.z), mk2(w[i4*4+2], w[i4*4+2]), acc);
                acc = FMA2(mk2(fa.w, fb.w), mk2(w[i4*4+3], w[i4*4+3]), acc);
            }
            #pragma unroll
            for (int i4 = 0; i4 < 4; ++i4) {
                float4 fa = Aa[i4], fb = Ab[i4];
                acc = FMA2(mk2(fa.x, fb.x), mk2(w[32+i4*4+0], w[32+i4*4+0]), acc);
                acc = FMA2(mk2(fa.y, fb.y), mk2(w[32+i4*4+1], w[32+i4*4+1]), acc);
                acc = FMA2(mk2(fa.z, fb.z), mk2(w[32+i4*4+2], w[32+i4*4+2]), acc);
                acc = FMA2(mk2(fa.w, fb.w), mk2(w[32+i4*4+3], w[32+i4*4+3]), acc);
            }
            BASEp[jja * 132 + kk] = acc.x;
            BASEp[jjb * 132 + kk] = acc.y;
        }
    }
    __syncthreads();

    // ---- per-block mask counts (held in regs until the atomic tail)
    float myCnt = 0.f;
    if (tid < 32) {
        #pragma unroll
        for (int jj = 0; jj < JT; ++jj) myCnt += MSp[tid * 17 + jj];
    }

    // ---- per-j LN1 stat scalars
    {
        const int jj = tid >> 4, p = tid & 15;
        const float* bp = BASEp + jj * 132 + p * 8;
        const float* wp = W0p + p * 8;
        float s0 = 0.f, s1 = 0.f, c1 = 0.f;
        #pragma unroll
        for (int i = 0; i < 8; ++i) {
            float v = bp[i], wv = wp[i];
            s0 += v; s1 = fmaf(v, v, s1); c1 = fmaf(v, wv, c1);
        }
        #pragma unroll
        for (int m = 1; m < 16; m <<= 1) {
            s0 += __shfl_xor(s0, m); s1 += __shfl_xor(s1, m); c1 += __shfl_xor(c1, m);
        }
        if (p == 0) {
            S0p[jj] = s0 * (1.f / HH);
            S1p[jj] = s1 * (1.f / HH);
            C1p[jj] = c1 * (1.f / HH);
        }
    }
    __syncthreads();

    f32x4 pool[2][2];   // [dt][bt]
    #pragma unroll
    for (int dt = 0; dt < 2; ++dt)
        #pragma unroll
        for (int bt = 0; bt < 2; ++bt)
            pool[dt][bt] = (f32x4){0.f, 0.f, 0.f, 0.f};

    #pragma unroll 1
    for (int jl = 0; jl < 4; ++jl) {
        const int jj = wslot * 4 + jl;
        const float x0  = XSp[n * 17 + jj];          // b = n        (bt=0)
        const float x1  = XSp[(16 + n) * 17 + jj];   // b = 16+n     (bt=1)
        const float mv0 = MSp[n * 17 + jj];
        const float mv1 = MSp[(16 + n) * 17 + jj];
        const float S0 = S0p[jj], S1 = S1p[jj], C1 = C1p[jj];

        float mu0 = fmaf(x0, mw0v, S0);
        float e0  = fmaf(x0 * x0, sw0v, fmaf(2.f * x0, C1, S1));
        float rs0 = rsqrtf(fmaxf(e0 - mu0 * mu0, 0.f) + EPSV);
        float cc0 = -mu0 * rs0;
        float mu1 = fmaf(x1, mw0v, S0);
        float e1  = fmaf(x1 * x1, sw0v, fmaf(2.f * x1, C1, S1));
        float rs1 = rsqrtf(fmaxf(e1 - mu1 * mu1, 0.f) + EPSV);
        float cc1 = -mu1 * rs1;

        f32x4 Cacc[2][2];   // [dt][bt]
        Cacc[0][0] = (f32x4){0.f,0.f,0.f,0.f}; Cacc[0][1] = (f32x4){0.f,0.f,0.f,0.f};
        Cacc[1][0] = (f32x4){0.f,0.f,0.f,0.f}; Cacc[1][1] = (f32x4){0.f,0.f,0.f,0.f};

        #pragma unroll
        for (int s = 0; s < 4; ++s) {
            const int off = 32 * s + 8 * q;
            const float* bp = BASEp + jj * 132 + off;
            union { short8 v; unsigned u[4]; } B0, B1;
            {   // first 4 k's
                float4 ba = *(const float4*)bp;
                float4 wa = *(const float4*)(W0p + off);
                float4 ga = *(const float4*)(G1p + off);
                float4 ca = *(const float4*)(B1p + off);
                B0.u[0] = pke(mk2(ba.x,ba.y), mk2(wa.x,wa.y), mk2(ga.x,ga.y), mk2(ca.x,ca.y), x0, rs0, cc0);
                B0.u[1] = pke(mk2(ba.z,ba.w), mk2(wa.z,wa.w), mk2(ga.z,ga.w), mk2(ca.z,ca.w), x0, rs0, cc0);
                B1.u[0] = pke(mk2(ba.x,ba.y), mk2(wa.x,wa.y), mk2(ga.x,ga.y), mk2(ca.x,ca.y), x1, rs1, cc1);
                B1.u[1] = pke(mk2(ba.z,ba.w), mk2(wa.z,wa.w), mk2(ga.z,ga.w), mk2(ca.z,ca.w), x1, rs1, cc1);
            }
            {   // second 4 k's
                float4 bb = *(const float4*)(bp + 4);
                float4 wb = *(const float4*)(W0p + off + 4);
                float4 gb = *(const float4*)(G1p + off + 4);
                float4 cb = *(const float4*)(B1p + off + 4);
                B0.u[2] = pke(mk2(bb.x,bb.y), mk2(wb.x,wb.y), mk2(gb.x,gb.y), mk2(cb.x,cb.y), x0, rs0, cc0);
                B0.u[3] = pke(mk2(bb.z,bb.w), mk2(wb.z,wb.w), mk2(gb.z,gb.w), mk2(cb.z,cb.w), x0, rs0, cc0);
                B1.u[2] = pke(mk2(bb.x,bb.y), mk2(wb.x,wb.y), mk2(gb.x,gb.y), mk2(cb.x,cb.y), x1, rs1, cc1);
                B1.u[3] = pke(mk2(bb.z,bb.w), mk2(wb.z,wb.w), mk2(gb.z,gb.w), mk2(cb.z,cb.w), x1, rs1, cc1);
            }
            union { short8 v; uint4 q4; } A0, A1;
            A0.q4 = AFl[(s * 2 + 0) * 64 + lane];
            A1.q4 = AFl[(s * 2 + 1) * 64 + lane];
            Cacc[0][0] = __builtin_amdgcn_mfma_f32_16x16x32_bf16(A0.v, B0.v, Cacc[0][0], 0, 0, 0);
            Cacc[0][1] = __builtin_amdgcn_mfma_f32_16x16x32_bf16(A0.v, B1.v, Cacc[0][1], 0, 0, 0);
            Cacc[1][0] = __builtin_amdgcn_mfma_f32_16x16x32_bf16(A1.v, B0.v, Cacc[1][0], 0, 0, 0);
            Cacc[1][1] = __builtin_amdgcn_mfma_f32_16x16x32_bf16(A1.v, B1.v, Cacc[1][1], 0, 0, 0);
        }

        // epilogue: C[d][b]; LN2 over d = 8 in-lane + 2 shfl per column b
        #pragma unroll
        for (int bt = 0; bt < 2; ++bt) {
            float v[8];
            float s = 0.f, ss = 0.f;
            #pragma unroll
            for (int dt = 0; dt < 2; ++dt)
                #pragma unroll
                for (int r = 0; r < 4; ++r) {
                    float t = Cacc[dt][bt][r] + hb2v[dt*4+r];
                    v[dt*4+r] = t;
                    s += t; ss = fmaf(t, t, ss);
                }
            s  += __shfl_xor(s, 16);  s  += __shfl_xor(s, 32);
            ss += __shfl_xor(ss, 16); ss += __shfl_xor(ss, 32);
            float mu  = s * (1.f / DD);
            float var = ss * (1.f / DD) - mu * mu;
            float rs  = rsqrtf(fmaxf(var, 0.f) + EPSV);
            float cc  = -mu * rs;
            float mv  = bt ? mv1 : mv0;
            #pragma unroll
            for (int dt = 0; dt < 2; ++dt)
                #pragma unroll
                for (int r = 0; r < 4; ++r) {
                    float t = fmaf(v[dt*4+r], rs, cc);
                    float h = fmaxf(fmaf(t, g2v[dt*4+r], B2v[dt*4+r]), 0.f);
                    pool[dt][bt][r] = fmaf(h, mv, pool[dt][bt][r]);
                }
        }
    }

    // ---- block reduce pooled tiles (padded stride 33)
    __syncthreads();
    #pragma unroll
    for (int dt = 0; dt < 2; ++dt)
        #pragma unroll
        for (int bt = 0; bt < 2; ++bt)
            #pragma unroll
            for (int r = 0; r < 4; ++r) {
                int d = dt * 16 + 4 * q + r, b = bt * 16 + n;
                smem[wslot * 1056 + b * 33 + d] = pool[dt][bt][r];
            }
    __syncthreads();
    const int rep = blockIdx.x & 31;
    float* acc2 = ws + WS_ACC + rep * 1024;
    for (int o = tid; o < 1024; o += 256) {
        int b = o >> 5, d = o & 31;
        int a = b * 33 + d;
        float sv = smem[a] + smem[1056 + a] + smem[2112 + a] + smem[3168 + a];
        atomicAdd(&acc2[o], sv);
    }
    if (tid < 32) atomicAdd(&ws[WS_CNT + rep * 32 + tid], myCnt);
}

// ---------------------------------------------------------------------------
// Kernel 2: single block x 1024 threads (16 waves; wave w owns batches
// {2w, 2w+1}). All weights staged to LDS with bulk independent loads first
// (single-block kernels die on serial HBM latency — measured R6: 40 µs at
// 0% busy). Compute is then LDS-only.
// ---------------------------------------------------------------------------
__global__ __launch_bounds__(1024) void k_final(
    const float* __restrict__ ws,
    const float* __restrict__ eW1,
    const float* __restrict__ eb1, const float* __restrict__ eg1,
    const float* __restrict__ eB1,
    const float* __restrict__ eW2,
    const float* __restrict__ eb2, const float* __restrict__ eg2,
    const float* __restrict__ eB2,
    float* __restrict__ out)
{
    const int tid  = threadIdx.x;
    const int lane = tid & 63;
    const int w    = tid >> 6;          // wave 0..15

    __shared__ float cS[32 * 33];       // pooled raw sums [b][d], padded
    __shared__ float cnS[32];           // 1/count
    __shared__ float W1s[32 * 256];     // eW1, 32 KB
    __shared__ float W2s[256 * 64];     // eW2, 64 KB
    __shared__ float eSh[32 * 256];     // e[b][i], 32 KB

    // ---- bulk stage: all global loads issued up front, independent
    #pragma unroll
    for (int o = tid; o < 2048; o += 1024)
        ((float4*)W1s)[o] = ((const float4*)eW1)[o];
    #pragma unroll
    for (int o = tid; o < 4096; o += 1024)
        ((float4*)W2s)[o] = ((const float4*)eW2)[o];
    {   // replica reduction: 1024 outputs, 32 replicas each (coalesced)
        float s = 0.f;
        #pragma unroll
        for (int r = 0; r < 32; ++r) s += ws[WS_ACC + r * 1024 + tid];
        int b = tid >> 5, d = tid & 31;
        cS[b * 33 + d] = s;
    }
    if (tid < 32) {
        float c = 0.f;
        #pragma unroll
        for (int r = 0; r < 32; ++r) c += ws[WS_CNT + r * 32 + tid];
        cnS[tid] = 1.f / fmaxf(c, 1.f);
    }
    // per-lane epilogue params (global, issued early too)
    float eb1v[4], g1v[4], B1v[4];
    #pragma unroll
    for (int i = 0; i < 4; ++i) {
        eb1v[i] = eb1[64 * i + lane];
        g1v[i]  = eg1[64 * i + lane];
        B1v[i]  = eB1[64 * i + lane];
    }
    const float eb2v = eb2[lane], g2v = eg2[lane], B2v = eB2[lane];
    __syncthreads();

    // ---- e-stage: wave w -> batches 2w, 2w+1; lane holds i = 64*ii + lane
    const int b0 = 2 * w, b1 = 2 * w + 1;
    const float icn0 = cnS[b0], icn1 = cnS[b1];
    float raw0[4] = {0.f, 0.f, 0.f, 0.f};
    float raw1[4] = {0.f, 0.f, 0.f, 0.f};
    #pragma unroll 4
    for (int d = 0; d < DD; ++d) {
        float c0 = cS[b0 * 33 + d], c1 = cS[b1 * 33 + d];
        #pragma unroll
        for (int i = 0; i < 4; ++i) {
            float wv = W1s[d * 256 + 64 * i + lane];
            raw0[i] = fmaf(c0, wv, raw0[i]);
            raw1[i] = fmaf(c1, wv, raw1[i]);
        }
    }
    #pragma unroll
    for (int pass = 0; pass < 2; ++pass) {
        const float icn = pass ? icn1 : icn0;
        const int   b   = pass ? b1 : b0;
        float* raw = pass ? raw1 : raw0;
        float ev[4], s = 0.f, ss = 0.f;
        #pragma unroll
        for (int i = 0; i < 4; ++i) {
            ev[i] = fmaf(raw[i], icn, eb1v[i]);
            s += ev[i]; ss = fmaf(ev[i], ev[i], ss);
        }
        #pragma unroll
        for (int m = 1; m < 64; m <<= 1) { s += __shfl_xor(s, m); ss += __shfl_xor(ss, m); }
        float mu  = s * (1.f / EHD);
        float var = ss * (1.f / EHD) - mu * mu;
        float rs  = rsqrtf(var + EPSV);
        float cc  = -mu * rs;
        #pragma unroll
        for (int i = 0; i < 4; ++i)
            eSh[b * 256 + 64 * i + lane] =
                fmaxf(fmaf(fmaf(ev[i], rs, cc), g1v[i], B1v[i]), 0.f);
    }
    __syncthreads();

    // ---- ml-stage: lane = output t; wave handles b0, b1
    float ml0 = eb2v, ml1 = eb2v;
    #pragma unroll 8
    for (int i = 0; i < EHD; ++i) {
        float wv = W2s[i * 64 + lane];
        ml0 = fmaf(eSh[b0 * 256 + i], wv, ml0);
        ml1 = fmaf(eSh[b1 * 256 + i], wv, ml1);
    }
    #pragma unroll
    for (int pass = 0; pass < 2; ++pass) {
        const int b = pass ? b1 : b0;
        float ml = pass ? ml1 : ml0;
        float s = ml, ss = ml * ml;
        #pragma unroll
        for (int m = 1; m < 64; m <<= 1) { s += __shfl_xor(s, m); ss += __shfl_xor(ss, m); }
        float mu  = s * (1.f / (2 * LATD));
        float var = ss * (1.f / (2 * LATD)) - mu * mu;
        float rs  = rsqrtf(var + EPSV);
        float v = fmaxf(fmaf(fmaf(ml, rs, -mu * rs), g2v, B2v), 0.f);
        if (lane < LATD) out[b * LATD + lane] = v;
        else             out[BATCH * LATD + b * LATD + (lane - LATD)] = v;
    }
}

extern "C" void kernel_launch(void* const* d_in, const int* in_sizes, int n_in,
                              void* d_out, int out_size, void* d_ws, size_t ws_size,
                              hipStream_t stream) {
    const float* x    = (const float*)d_in[0];
    const int*   mask = (const int*)  d_in[1];
    const int*   aidx = (const int*)  d_in[2];
    const float* F    = (const float*)d_in[3];
    const float* AeE  = (const float*)d_in[4];
    const float* hW1  = (const float*)d_in[5];
    const float* hb1  = (const float*)d_in[6];
    const float* hg1  = (const float*)d_in[7];
    const float* hB1  = (const float*)d_in[8];
    const float* hW2  = (const float*)d_in[9];
    const float* hb2  = (const float*)d_in[10];
    const float* hg2  = (const float*)d_in[11];
    const float* hB2  = (const float*)d_in[12];
    const float* eW1  = (const float*)d_in[13];
    const float* eb1  = (const float*)d_in[14];
    const float* eg1  = (const float*)d_in[15];
    const float* eB1  = (const float*)d_in[16];
    const float* eW2  = (const float*)d_in[17];
    const float* eb2  = (const float*)d_in[18];
    const float* eg2  = (const float*)d_in[19];
    const float* eB2  = (const float*)d_in[20];
    float* out = (float*)d_out;
    float* ws  = (float*)d_ws;

    k_zero<<<dim3(34), dim3(256), 0, stream>>>(ws, hW1, hW2, hb2, hg2, hB2);
    k_rows<<<dim3(NBLK), dim3(256), 0, stream>>>(
        x, mask, aidx, F, AeE, hW1, hb1, hg1, hB1, ws);
    k_final<<<dim3(1), dim3(1024), 0, stream>>>(
        ws, eW1, eb1, eg1, eB1, eW2, eb2, eg2, eB2, out);
}

// Round 10
// 146.132 us; speedup vs baseline: 1.2941x; 1.2941x over previous
//
#include <hip/hip_runtime.h>
#include <hip/hip_bf16.h>

#define JTOT  16384
#define BATCH 32
#define DD    32
#define AE    16
#define HH    128
#define EHD   256
#define LATD  32
#define JT    16      // j per block
#define NBLK  1024    // k_rows blocks
#define EPSV  1e-5f

// workspace layout (floats):
//   acc2[32][1024] pooled replicas, cnt2[32][32] counts  (zeroed)
//   AF: per-lane prepacked bf16 W2^T fragments (64 lanes x 32 dwords)
//   EP: per-lane epilogue params (64 lanes x 24 floats)
//   MW: mean(w0), mean(w0^2)
#define WS_ACC   0
#define WS_CNT   32768
#define WS_ZEND  33792   // floats to zero
#define WS_AF    33792   // 2048 floats (dword-punned)
#define WS_EP    35840   // 1536 floats
#define WS_MW    37376   // 2 floats

typedef __attribute__((ext_vector_type(8))) short short8;
typedef __attribute__((ext_vector_type(4))) float f32x4;
typedef __attribute__((ext_vector_type(2))) float v2f;

static __device__ __forceinline__ v2f mk2(float a, float b) {
    v2f r; r.x = a; r.y = b; return r;
}
static __device__ __forceinline__ v2f FMA2(v2f a, v2f b, v2f c) {
#if __has_builtin(__builtin_elementwise_fma)
    return __builtin_elementwise_fma(a, b, c);
#else
    v2f r; r.x = fmaf(a.x, b.x, c.x); r.y = fmaf(a.y, b.y, c.y); return r;
#endif
}
static __device__ __forceinline__ v2f MAX2(v2f a, v2f b) {
#if __has_builtin(__builtin_elementwise_max)
    return __builtin_elementwise_max(a, b);
#else
    v2f r; r.x = fmaxf(a.x, b.x); r.y = fmaxf(a.y, b.y); return r;
#endif
}

// LDS float offsets (k_rows)
#define OFF_BASE 0      // 16*132 = 2112
#define OFF_XS   2112   // 32*17  = 544
#define OFF_MS   2656   // 32*17  = 544
#define OFF_W0   3200   // 128
#define OFF_G1   3328   // 128
#define OFF_B1   3456   // 128
#define OFF_S0   3584   // 16
#define OFF_S1   3600   // 16
#define OFF_C1   3616   // 16
#define LDS_FLOATS 4224 // pool reduce reuses smem: 4 slots * 1056

__device__ __forceinline__ unsigned pk2(float lo, float hi) {
    float2 f; f.x = lo; f.y = hi;
    __hip_bfloat162 h = __float22bfloat162_rn(f);
    unsigned u; __builtin_memcpy(&u, &h, 4);
    return u;
}

// normalized-relu'd h1 for 2 consecutive k, packed to 2xbf16
__device__ __forceinline__ unsigned pke(v2f b, v2f w, v2f g, v2f Bl,
                                        float x, float rs, float cc) {
    v2f u = FMA2(mk2(x, x), w, b);            // h1 = base + x*w0
    v2f t = FMA2(u, mk2(rs, rs), mk2(cc, cc));
    v2f h = FMA2(t, g, Bl);
    h = MAX2(h, mk2(0.f, 0.f));
    return pk2(h.x, h.y);
}

// ---------------------------------------------------------------------------
// Kernel 0: blocks 0..32 zero the accumulator region (poisoned 0xAA each
// call). Block 33 precomputes the block-invariant k_rows prologue data:
// per-lane bf16 W2^T fragments, per-lane epilogue params, w0 moments.
// ---------------------------------------------------------------------------
__global__ __launch_bounds__(256) void k_zero(
    float* __restrict__ ws, const float* __restrict__ hW1,
    const float* __restrict__ hW2, const float* __restrict__ hb2,
    const float* __restrict__ hg2, const float* __restrict__ hB2)
{
    if (blockIdx.x < 33) {
        int i = (blockIdx.x * 256 + threadIdx.x) * 4;
        *(float4*)(ws + i) = (float4){0.f, 0.f, 0.f, 0.f};
        return;
    }
    const int tid = threadIdx.x;
    if (tid >= 64) return;
    const int lane = tid, n = lane & 15, q = lane >> 4;

    // AF: A[m=d (dt*16+n)][k=32s+8q+i], packed pairs along k
    unsigned* afp = (unsigned*)(ws + WS_AF) + lane * 32;
    #pragma unroll
    for (int s = 0; s < 4; ++s)
        #pragma unroll
        for (int dt = 0; dt < 2; ++dt)
            #pragma unroll
            for (int p2 = 0; p2 < 4; ++p2) {
                int k0 = 32 * s + 8 * q + 2 * p2;
                afp[(s * 2 + dt) * 4 + p2] =
                    pk2(hW2[(k0    ) * DD + dt * 16 + n],
                        hW2[(k0 + 1) * DD + dt * 16 + n]);
            }

    // EP: d = dt*16 + 4q + r
    float* epp = ws + WS_EP + lane * 24;
    #pragma unroll
    for (int dt = 0; dt < 2; ++dt)
        #pragma unroll
        for (int r = 0; r < 4; ++r) {
            int d = dt * 16 + 4 * q + r;
            epp[dt * 4 + r]      = hb2[d];
            epp[8 + dt * 4 + r]  = hg2[d];
            epp[16 + dt * 4 + r] = hB2[d];
        }

    // MW: mean(w0), mean(w0^2)
    {
        float a = hW1[lane], b = hW1[64 + lane];
        float s = a + b, qq = fmaf(a, a, b * b);
        #pragma unroll
        for (int m = 1; m < 64; m <<= 1) { s += __shfl_xor(s, m); qq += __shfl_xor(qq, m); }
        if (lane == 0) { ws[WS_MW] = s * (1.f / HH); ws[WS_MW + 1] = qq * (1.f / HH); }
    }
}

// ---------------------------------------------------------------------------
// Kernel 1: 1024 blocks x 256 threads, 16 j each. Transposed MFMA:
// A = W2^T (d x K, bf16, preloaded from ws), B = normalized h1^T (K x b),
// C = d x b.
// Register discipline (gfx950 unified VGPR+AGPR, ~190 regs true need):
//   (256,2) -> VGPR=128 arch + AGPR, zero spill, 2 waves/EU  [R8: 46 us]
//   (256,3) -> spills ~148 MB scratch                        [R9: 86 us]
//   (256,4) -> spills ~300 MB scratch                        [R4: 99 us]
// Keep (256,2). Tail: atomicAdd pooled tile into acc2[blk&31].
// ---------------------------------------------------------------------------
__global__ __launch_bounds__(256, 2) void k_rows(
    const float* __restrict__ x, const int* __restrict__ mask,
    const int* __restrict__ aidx, const float* __restrict__ F,
    const float* __restrict__ AeE, const float* __restrict__ hW1,
    const float* __restrict__ hb1, const float* __restrict__ hg1,
    const float* __restrict__ hB1, float* __restrict__ ws)
{
    __shared__ float smem[LDS_FLOATS];
    const int tid = threadIdx.x;
    const int j0  = blockIdx.x * JT;

    float* BASEp = smem + OFF_BASE;   // [16 j][132]
    float* XSp   = smem + OFF_XS;     // [32 b][17]
    float* MSp   = smem + OFF_MS;     // [32 b][17]
    float* W0p   = smem + OFF_W0;
    float* G1p   = smem + OFF_G1;
    float* B1p   = smem + OFF_B1;
    float* S0p   = smem + OFF_S0;
    float* S1p   = smem + OFF_S1;
    float* C1p   = smem + OFF_C1;

    const int lane = tid & 63;
    const int n = lane & 15, q = lane >> 4;
    const int wslot = tid >> 6;

    // ---- preloaded block-invariant data (coalesced vector loads from ws)
    short8 Af[4][2];
    {
        const uint4* afq = (const uint4*)((const unsigned*)(ws + WS_AF) + lane * 32);
        #pragma unroll
        for (int s = 0; s < 4; ++s)
            #pragma unroll
            for (int dt = 0; dt < 2; ++dt) {
                union { short8 v; uint4 u; } t;
                t.u = afq[s * 2 + dt];
                Af[s][dt] = t.v;
            }
    }
    float hb2v[8], g2v[8], B2v[8];
    {
        const float4* ep4 = (const float4*)(ws + WS_EP + lane * 24);
        float4 a0 = ep4[0], a1 = ep4[1], a2 = ep4[2], a3 = ep4[3], a4 = ep4[4], a5 = ep4[5];
        hb2v[0]=a0.x; hb2v[1]=a0.y; hb2v[2]=a0.z; hb2v[3]=a0.w;
        hb2v[4]=a1.x; hb2v[5]=a1.y; hb2v[6]=a1.z; hb2v[7]=a1.w;
        g2v[0]=a2.x;  g2v[1]=a2.y;  g2v[2]=a2.z;  g2v[3]=a2.w;
        g2v[4]=a3.x;  g2v[5]=a3.y;  g2v[6]=a3.z;  g2v[7]=a3.w;
        B2v[0]=a4.x;  B2v[1]=a4.y;  B2v[2]=a4.z;  B2v[3]=a4.w;
        B2v[4]=a5.x;  B2v[5]=a5.y;  B2v[6]=a5.z;  B2v[7]=a5.w;
    }
    const float mw0v = ws[WS_MW], sw0v = ws[WS_MW + 1];

    // ---- stage x, mask, LN1 params
    for (int o = tid; o < 512; o += 256) {
        int b = o >> 4, jj = o & 15;
        XSp[b * 17 + jj] = x[b * JTOT + j0 + jj];
        MSp[b * 17 + jj] = (float)mask[b * JTOT + j0 + jj];
    }
    if (tid < HH) { W0p[tid] = hW1[tid]; G1p[tid] = hg1[tid]; B1p[tid] = hB1[tid]; }

    // ---- base[j][k] (b-independent part of layer 1), packed fp32 over j-pairs
    {
        const int kk = tid & 127;
        const int jh = tid >> 7;           // 0..1
        float w[48];
        #pragma unroll
        for (int i = 0; i < 48; ++i) w[i] = hW1[(1 + i) * HH + kk];
        const float hb1v = hb1[kk];
        #pragma unroll
        for (int pr = 0; pr < 4; ++pr) {
            const int jja = 4 * pr + jh, jjb = jja + 2;
            const float4* Fa = (const float4*)(F + (j0 + jja) * DD);
            const float4* Fb = (const float4*)(F + (j0 + jjb) * DD);
            const float4* Aa = (const float4*)(AeE + aidx[j0 + jja] * AE);
            const float4* Ab = (const float4*)(AeE + aidx[j0 + jjb] * AE);
            v2f acc = mk2(hb1v, hb1v);
            #pragma unroll
            for (int i4 = 0; i4 < 8; ++i4) {
                float4 fa = Fa[i4], fb = Fb[i4];
                acc = FMA2(mk2(fa.x, fb.x), mk2(w[i4*4+0], w[i4*4+0]), acc);
                acc = FMA2(mk2(fa.y, fb.y), mk2(w[i4*4+1], w[i4*4+1]), acc);
                acc = FMA2(mk2(fa.z, fb.z), mk2(w[i4*4+2], w[i4*4+2]), acc);
                acc = FMA2(mk2(fa.w, fb.w), mk2(w[i4*4+3], w[i4*4+3]), acc);
            }
            #pragma unroll
            for (int i4 = 0; i4 < 4; ++i4) {
                float4 fa = Aa[i4], fb = Ab[i4];
                acc = FMA2(mk2(fa.x, fb.x), mk2(w[32+i4*4+0], w[32+i4*4+0]), acc);
                acc = FMA2(mk2(fa.y, fb.y), mk2(w[32+i4*4+1], w[32+i4*4+1]), acc);
                acc = FMA2(mk2(fa.z, fb.z), mk2(w[32+i4*4+2], w[32+i4*4+2]), acc);
                acc = FMA2(mk2(fa.w, fb.w), mk2(w[32+i4*4+3], w[32+i4*4+3]), acc);
            }
            BASEp[jja * 132 + kk] = acc.x;
            BASEp[jjb * 132 + kk] = acc.y;
        }
    }
    __syncthreads();

    // ---- per-block mask counts (held in regs until the atomic tail)
    float myCnt = 0.f;
    if (tid < 32) {
        #pragma unroll
        for (int jj = 0; jj < JT; ++jj) myCnt += MSp[tid * 17 + jj];
    }

    // ---- per-j LN1 stat scalars
    {
        const int jj = tid >> 4, p = tid & 15;
        const float* bp = BASEp + jj * 132 + p * 8;
        const float* wp = W0p + p * 8;
        float s0 = 0.f, s1 = 0.f, c1 = 0.f;
        #pragma unroll
        for (int i = 0; i < 8; ++i) {
            float v = bp[i], wv = wp[i];
            s0 += v; s1 = fmaf(v, v, s1); c1 = fmaf(v, wv, c1);
        }
        #pragma unroll
        for (int m = 1; m < 16; m <<= 1) {
            s0 += __shfl_xor(s0, m); s1 += __shfl_xor(s1, m); c1 += __shfl_xor(c1, m);
        }
        if (p == 0) {
            S0p[jj] = s0 * (1.f / HH);
            S1p[jj] = s1 * (1.f / HH);
            C1p[jj] = c1 * (1.f / HH);
        }
    }
    __syncthreads();

    f32x4 pool[2][2];   // [dt][bt]
    #pragma unroll
    for (int dt = 0; dt < 2; ++dt)
        #pragma unroll
        for (int bt = 0; bt < 2; ++bt)
            pool[dt][bt] = (f32x4){0.f, 0.f, 0.f, 0.f};

    #pragma unroll 1
    for (int jl = 0; jl < 4; ++jl) {
        const int jj = wslot * 4 + jl;
        const float x0  = XSp[n * 17 + jj];          // b = n        (bt=0)
        const float x1  = XSp[(16 + n) * 17 + jj];   // b = 16+n     (bt=1)
        const float mv0 = MSp[n * 17 + jj];
        const float mv1 = MSp[(16 + n) * 17 + jj];
        const float S0 = S0p[jj], S1 = S1p[jj], C1 = C1p[jj];

        float mu0 = fmaf(x0, mw0v, S0);
        float e0  = fmaf(x0 * x0, sw0v, fmaf(2.f * x0, C1, S1));
        float rs0 = rsqrtf(fmaxf(e0 - mu0 * mu0, 0.f) + EPSV);
        float cc0 = -mu0 * rs0;
        float mu1 = fmaf(x1, mw0v, S0);
        float e1  = fmaf(x1 * x1, sw0v, fmaf(2.f * x1, C1, S1));
        float rs1 = rsqrtf(fmaxf(e1 - mu1 * mu1, 0.f) + EPSV);
        float cc1 = -mu1 * rs1;

        f32x4 Cacc[2][2];   // [dt][bt]
        Cacc[0][0] = (f32x4){0.f,0.f,0.f,0.f}; Cacc[0][1] = (f32x4){0.f,0.f,0.f,0.f};
        Cacc[1][0] = (f32x4){0.f,0.f,0.f,0.f}; Cacc[1][1] = (f32x4){0.f,0.f,0.f,0.f};

        #pragma unroll
        for (int s = 0; s < 4; ++s) {
            const int off = 32 * s + 8 * q;
            const float* bp = BASEp + jj * 132 + off;
            union { short8 v; unsigned u[4]; } B0, B1;
            {   // first 4 k's
                float4 ba = *(const float4*)bp;
                float4 wa = *(const float4*)(W0p + off);
                float4 ga = *(const float4*)(G1p + off);
                float4 ca = *(const float4*)(B1p + off);
                B0.u[0] = pke(mk2(ba.x,ba.y), mk2(wa.x,wa.y), mk2(ga.x,ga.y), mk2(ca.x,ca.y), x0, rs0, cc0);
                B0.u[1] = pke(mk2(ba.z,ba.w), mk2(wa.z,wa.w), mk2(ga.z,ga.w), mk2(ca.z,ca.w), x0, rs0, cc0);
                B1.u[0] = pke(mk2(ba.x,ba.y), mk2(wa.x,wa.y), mk2(ga.x,ga.y), mk2(ca.x,ca.y), x1, rs1, cc1);
                B1.u[1] = pke(mk2(ba.z,ba.w), mk2(wa.z,wa.w), mk2(ga.z,ga.w), mk2(ca.z,ca.w), x1, rs1, cc1);
            }
            {   // second 4 k's
                float4 bb = *(const float4*)(bp + 4);
                float4 wb = *(const float4*)(W0p + off + 4);
                float4 gb = *(const float4*)(G1p + off + 4);
                float4 cb = *(const float4*)(B1p + off + 4);
                B0.u[2] = pke(mk2(bb.x,bb.y), mk2(wb.x,wb.y), mk2(gb.x,gb.y), mk2(cb.x,cb.y), x0, rs0, cc0);
                B0.u[3] = pke(mk2(bb.z,bb.w), mk2(wb.z,wb.w), mk2(gb.z,gb.w), mk2(cb.z,cb.w), x0, rs0, cc0);
                B1.u[2] = pke(mk2(bb.x,bb.y), mk2(wb.x,wb.y), mk2(gb.x,gb.y), mk2(cb.x,cb.y), x1, rs1, cc1);
                B1.u[3] = pke(mk2(bb.z,bb.w), mk2(wb.z,wb.w), mk2(gb.z,gb.w), mk2(cb.z,cb.w), x1, rs1, cc1);
            }
            Cacc[0][0] = __builtin_amdgcn_mfma_f32_16x16x32_bf16(Af[s][0], B0.v, Cacc[0][0], 0, 0, 0);
            Cacc[0][1] = __builtin_amdgcn_mfma_f32_16x16x32_bf16(Af[s][0], B1.v, Cacc[0][1], 0, 0, 0);
            Cacc[1][0] = __builtin_amdgcn_mfma_f32_16x16x32_bf16(Af[s][1], B0.v, Cacc[1][0], 0, 0, 0);
            Cacc[1][1] = __builtin_amdgcn_mfma_f32_16x16x32_bf16(Af[s][1], B1.v, Cacc[1][1], 0, 0, 0);
        }

        // epilogue: C[d][b]; LN2 over d = 8 in-lane + 2 shfl per column b
        #pragma unroll
        for (int bt = 0; bt < 2; ++bt) {
            float v[8];
            float s = 0.f, ss = 0.f;
            #pragma unroll
            for (int dt = 0; dt < 2; ++dt)
                #pragma unroll
                for (int r = 0; r < 4; ++r) {
                    float t = Cacc[dt][bt][r] + hb2v[dt*4+r];
                    v[dt*4+r] = t;
                    s += t; ss = fmaf(t, t, ss);
                }
            s  += __shfl_xor(s, 16);  s  += __shfl_xor(s, 32);
            ss += __shfl_xor(ss, 16); ss += __shfl_xor(ss, 32);
            float mu  = s * (1.f / DD);
            float var = ss * (1.f / DD) - mu * mu;
            float rs  = rsqrtf(fmaxf(var, 0.f) + EPSV);
            float cc  = -mu * rs;
            float mv  = bt ? mv1 : mv0;
            #pragma unroll
            for (int dt = 0; dt < 2; ++dt)
                #pragma unroll
                for (int r = 0; r < 4; ++r) {
                    float t = fmaf(v[dt*4+r], rs, cc);
                    float h = fmaxf(fmaf(t, g2v[dt*4+r], B2v[dt*4+r]), 0.f);
                    pool[dt][bt][r] = fmaf(h, mv, pool[dt][bt][r]);
                }
        }
    }

    // ---- block reduce pooled tiles (padded stride 33: conflict-free)
    __syncthreads();
    #pragma unroll
    for (int dt = 0; dt < 2; ++dt)
        #pragma unroll
        for (int bt = 0; bt < 2; ++bt)
            #pragma unroll
            for (int r = 0; r < 4; ++r) {
                int d = dt * 16 + 4 * q + r, b = bt * 16 + n;
                smem[wslot * 1056 + b * 33 + d] = pool[dt][bt][r];
            }
    __syncthreads();
    const int rep = blockIdx.x & 31;
    float* acc2 = ws + WS_ACC + rep * 1024;
    for (int o = tid; o < 1024; o += 256) {
        int b = o >> 5, d = o & 31;
        int a = b * 33 + d;
        float sv = smem[a] + smem[1056 + a] + smem[2112 + a] + smem[3168 + a];
        atomicAdd(&acc2[o], sv);
    }
    if (tid < 32) atomicAdd(&ws[WS_CNT + rep * 32 + tid], myCnt);
}

// ---------------------------------------------------------------------------
// Kernel 2: single block x 1024 threads (16 waves; wave w owns batches
// {2w, 2w+1}). All weights staged to LDS with bulk independent loads first
// (single-block kernels die on serial HBM latency — measured R6: 40 µs at
// 0% busy). Compute is then LDS-only.
// ---------------------------------------------------------------------------
__global__ __launch_bounds__(1024) void k_final(
    const float* __restrict__ ws,
    const float* __restrict__ eW1,
    const float* __restrict__ eb1, const float* __restrict__ eg1,
    const float* __restrict__ eB1,
    const float* __restrict__ eW2,
    const float* __restrict__ eb2, const float* __restrict__ eg2,
    const float* __restrict__ eB2,
    float* __restrict__ out)
{
    const int tid  = threadIdx.x;
    const int lane = tid & 63;
    const int w    = tid >> 6;          // wave 0..15

    __shared__ float cS[32 * 33];       // pooled raw sums [b][d], padded
    __shared__ float cnS[32];           // 1/count
    __shared__ float W1s[32 * 256];     // eW1, 32 KB
    __shared__ float W2s[256 * 64];     // eW2, 64 KB
    __shared__ float eSh[32 * 256];     // e[b][i], 32 KB

    // ---- bulk stage: all global loads issued up front, independent
    #pragma unroll
    for (int o = tid; o < 2048; o += 1024)
        ((float4*)W1s)[o] = ((const float4*)eW1)[o];
    #pragma unroll
    for (int o = tid; o < 4096; o += 1024)
        ((float4*)W2s)[o] = ((const float4*)eW2)[o];
    {   // replica reduction: 1024 outputs, 32 replicas each (coalesced)
        float s = 0.f;
        #pragma unroll
        for (int r = 0; r < 32; ++r) s += ws[WS_ACC + r * 1024 + tid];
        int b = tid >> 5, d = tid & 31;
        cS[b * 33 + d] = s;
    }
    if (tid < 32) {
        float c = 0.f;
        #pragma unroll
        for (int r = 0; r < 32; ++r) c += ws[WS_CNT + r * 32 + tid];
        cnS[tid] = 1.f / fmaxf(c, 1.f);
    }
    // per-lane epilogue params (global, issued early too)
    float eb1v[4], g1v[4], B1v[4];
    #pragma unroll
    for (int i = 0; i < 4; ++i) {
        eb1v[i] = eb1[64 * i + lane];
        g1v[i]  = eg1[64 * i + lane];
        B1v[i]  = eB1[64 * i + lane];
    }
    const float eb2v = eb2[lane], g2v = eg2[lane], B2v = eB2[lane];
    __syncthreads();

    // ---- e-stage: wave w -> batches 2w, 2w+1; lane holds i = 64*ii + lane
    const int b0 = 2 * w, b1 = 2 * w + 1;
    const float icn0 = cnS[b0], icn1 = cnS[b1];
    float raw0[4] = {0.f, 0.f, 0.f, 0.f};
    float raw1[4] = {0.f, 0.f, 0.f, 0.f};
    #pragma unroll 4
    for (int d = 0; d < DD; ++d) {
        float c0 = cS[b0 * 33 + d], c1 = cS[b1 * 33 + d];
        #pragma unroll
        for (int i = 0; i < 4; ++i) {
            float wv = W1s[d * 256 + 64 * i + lane];
            raw0[i] = fmaf(c0, wv, raw0[i]);
            raw1[i] = fmaf(c1, wv, raw1[i]);
        }
    }
    #pragma unroll
    for (int pass = 0; pass < 2; ++pass) {
        const float icn = pass ? icn1 : icn0;
        const int   b   = pass ? b1 : b0;
        float* raw = pass ? raw1 : raw0;
        float ev[4], s = 0.f, ss = 0.f;
        #pragma unroll
        for (int i = 0; i < 4; ++i) {
            ev[i] = fmaf(raw[i], icn, eb1v[i]);
            s += ev[i]; ss = fmaf(ev[i], ev[i], ss);
        }
        #pragma unroll
        for (int m = 1; m < 64; m <<= 1) { s += __shfl_xor(s, m); ss += __shfl_xor(ss, m); }
        float mu  = s * (1.f / EHD);
        float var = ss * (1.f / EHD) - mu * mu;
        float rs  = rsqrtf(var + EPSV);
        float cc  = -mu * rs;
        #pragma unroll
        for (int i = 0; i < 4; ++i)
            eSh[b * 256 + 64 * i + lane] =
                fmaxf(fmaf(fmaf(ev[i], rs, cc), g1v[i], B1v[i]), 0.f);
    }
    __syncthreads();

    // ---- ml-stage: lane = output t; wave handles b0, b1
    float ml0 = eb2v, ml1 = eb2v;
    #pragma unroll 8
    for (int i = 0; i < EHD; ++i) {
        float wv = W2s[i * 64 + lane];
        ml0 = fmaf(eSh[b0 * 256 + i], wv, ml0);
        ml1 = fmaf(eSh[b1 * 256 + i], wv, ml1);
    }
    #pragma unroll
    for (int pass = 0; pass < 2; ++pass) {
        const int b = pass ? b1 : b0;
        float ml = pass ? ml1 : ml0;
        float s = ml, ss = ml * ml;
        #pragma unroll
        for (int m = 1; m < 64; m <<= 1) { s += __shfl_xor(s, m); ss += __shfl_xor(ss, m); }
        float mu  = s * (1.f / (2 * LATD));
        float var = ss * (1.f / (2 * LATD)) - mu * mu;
        float rs  = rsqrtf(var + EPSV);
        float v = fmaxf(fmaf(fmaf(ml, rs, -mu * rs), g2v, B2v), 0.f);
        if (lane < LATD) out[b * LATD + lane] = v;
        else             out[BATCH * LATD + b * LATD + (lane - LATD)] = v;
    }
}

extern "C" void kernel_launch(void* const* d_in, const int* in_sizes, int n_in,
                              void* d_out, int out_size, void* d_ws, size_t ws_size,
                              hipStream_t stream) {
    const float* x    = (const float*)d_in[0];
    const int*   mask = (const int*)  d_in[1];
    const int*   aidx = (const int*)  d_in[2];
    const float* F    = (const float*)d_in[3];
    const float* AeE  = (const float*)d_in[4];
    const float* hW1  = (const float*)d_in[5];
    const float* hb1  = (const float*)d_in[6];
    const float* hg1  = (const float*)d_in[7];
    const float* hB1  = (const float*)d_in[8];
    const float* hW2  = (const float*)d_in[9];
    const float* hb2  = (const float*)d_in[10];
    const float* hg2  = (const float*)d_in[11];
    const float* hB2  = (const float*)d_in[12];
    const float* eW1  = (const float*)d_in[13];
    const float* eb1  = (const float*)d_in[14];
    const float* eg1  = (const float*)d_in[15];
    const float* eB1  = (const float*)d_in[16];
    const float* eW2  = (const float*)d_in[17];
    const float* eb2  = (const float*)d_in[18];
    const float* eg2  = (const float*)d_in[19];
    const float* eB2  = (const float*)d_in[20];
    float* out = (float*)d_out;
    float* ws  = (float*)d_ws;

    k_zero<<<dim3(34), dim3(256), 0, stream>>>(ws, hW1, hW2, hb2, hg2, hB2);
    k_rows<<<dim3(NBLK), dim3(256), 0, stream>>>(
        x, mask, aidx, F, AeE, hW1, hb1, hg1, hB1, ws);
    k_final<<<dim3(1), dim3(1024), 0, stream>>>(
        ws, eW1, eb1, eg1, eB1, eW2, eb2, eg2, eB2, out);
}